// Round 15
// baseline (871808.301 us; speedup 1.0000x reference)
//
#include <hip/hip_runtime.h>
#include <cstdint>
#include <cstddef>

typedef _Float16 f16;
typedef _Float16 f16x8 __attribute__((ext_vector_type(8)));
typedef float f32x4 __attribute__((ext_vector_type(4)));
typedef unsigned u32x4 __attribute__((ext_vector_type(4)));
typedef unsigned long long u64;

#define NWG 256
#define WGSZ 256
#define RL 16     // local/mirror ring depth (16 % 3 == 1 -> stale tag differs)
#define RC 32     // canonical ring depth (32 % 3 == 2 -> stale tag differs)
#define BAIL 20000  // coh spin cap (terminate-with-garbage rather than hang)
#define MCAP 48     // local fast-path tries before canonical fallback

namespace gru {

__device__ inline f32x4 mf(f16x8 a, f16x8 b, f32x4 c) {
  return __builtin_amdgcn_mfma_f32_16x16x32_f16(a, b, c, 0, 0, 0);
}
__device__ inline float sigf(float x) { return 1.f / (1.f + __expf(-x)); }
__device__ inline float tanh_fast(float x) {
  float xx = fminf(fmaxf(x, -15.f), 15.f);
  float e = __expf(-2.f * xx);
  return (1.f - e) / (1.f + e);
}
__device__ inline unsigned tag_of(int t) { return 1u + (unsigned)(t % 3); }

struct SMem {
  f16 wI[96 * 64 * 8];    // 96 KB: input-weight slice (L0: wih0 full; L1: wih1 K-half0), swizzled
  float sc[3][8][4][64];  // 24 KB: cross-wave reduce scratch
  float hm[16][32];       // fp32 master h tile (16 batch rows x 32 own cols)
  float pad[512];         // keep LDS > 80KB total -> 1 block/CU
};

struct Args {
  const f16* x16;   // [1024][64][512]
  const float* bih0; const float* bhh0; const float* bih1; const float* bhh1; const float* bout;
  const f16* wih0; const f16* whh0; const f16* wih1; const f16* whh1; const f16* wout;
  f16* hl;   // local rings   [(g*2+l)][RL][16][1024] — plain stores, same-XCD sc0 reads
  f16* hc;   // canonical     [(g*2+l)][RC][16][1024] — sc0sc1 WT, always correct
  f16* hm0;  // h0 mirror on L1 XCDs [g][RL][16][1024] — relay-published
  float* out;
  unsigned* prog;  // per g: 32 counters x 32-dword stride (L1 progress)
};

__device__ inline unsigned aldu(const unsigned* p) {
  return __hip_atomic_load(p, __ATOMIC_RELAXED, __HIP_MEMORY_SCOPE_AGENT);
}
__device__ inline void astu(unsigned* p, unsigned v) {
  __hip_atomic_store(p, v, __ATOMIC_RELAXED, __HIP_MEMORY_SCOPE_AGENT);
}
__device__ inline void st8_sys(f16* p, u64 v) {
  __hip_atomic_store((u64*)p, v, __ATOMIC_RELAXED, __HIP_MEMORY_SCOPE_SYSTEM);
}

struct frag4 { f16x8 v[4]; };

__device__ inline frag4 ld4_l2(const f16* p) {  // sc0: bypass L1, served by own-XCD L2
  frag4 f;
  asm volatile(
      "global_load_dwordx4 %0, %4, off sc0\n\t"
      "global_load_dwordx4 %1, %4, off offset:64 sc0\n\t"
      "global_load_dwordx4 %2, %4, off offset:128 sc0\n\t"
      "global_load_dwordx4 %3, %4, off offset:192 sc0\n\t"
      "s_waitcnt vmcnt(0)"
      : "=&v"(f.v[0]), "=&v"(f.v[1]), "=&v"(f.v[2]), "=&v"(f.v[3])
      : "v"(p) : "memory");
  return f;
}
__device__ inline frag4 ld4_coh(const f16* p) {  // sc0 sc1: coherent point (proven R12)
  frag4 f;
  asm volatile(
      "global_load_dwordx4 %0, %4, off sc0 sc1\n\t"
      "global_load_dwordx4 %1, %4, off offset:64 sc0 sc1\n\t"
      "global_load_dwordx4 %2, %4, off offset:128 sc0 sc1\n\t"
      "global_load_dwordx4 %3, %4, off offset:192 sc0 sc1\n\t"
      "s_waitcnt vmcnt(0)"
      : "=&v"(f.v[0]), "=&v"(f.v[1]), "=&v"(f.v[2]), "=&v"(f.v[3])
      : "v"(p) : "memory");
  return f;
}
__device__ inline int vfrag4(const frag4& f, unsigned ep) {
  unsigned acc = 0;
#pragma unroll
  for (int r = 0; r < 4; ++r) {
    u32x4 w = __builtin_bit_cast(u32x4, f.v[r]);
    acc |= ((w[0] & 0x30003u) ^ ep) | ((w[1] & 0x30003u) ^ ep) |
           ((w[2] & 0x30003u) ^ ep) | ((w[3] & 0x30003u) ^ ep);
  }
  return acc == 0;
}
// Canonical validated read, CAPPED (never hangs; cap-exhaust = wrong-but-done).
__device__ inline frag4 ld4_val(const f16* p, unsigned ep) {
  frag4 f = ld4_coh(p);
  for (int it = 0; it < BAIL && !__all(vfrag4(f, ep)); ++it) {
    __builtin_amdgcn_s_sleep(1);
    f = ld4_coh(p);
  }
  return f;
}
// Local (same-XCD L2) fast path with canonical fallback.
__device__ inline frag4 ld4_fast(const f16* lp, const f16* cp, unsigned ep) {
  frag4 f = ld4_l2(lp);
  for (int it = 0; it < MCAP && !__all(vfrag4(f, ep)); ++it) {
    __builtin_amdgcn_s_sleep(1);
    f = ld4_l2(lp);
  }
  if (!__all(vfrag4(f, ep))) f = ld4_val(cp, ep);
  return f;
}

__device__ inline u64 pack4(const float* hn4, int lr, unsigned wtag) {
  u64 w = 0;
#pragma unroll
  for (int q = 0; q < 4; ++q) {
    f16 h = (f16)hn4[q];
    unsigned own = ((unsigned)__builtin_bit_cast(unsigned short, h) & 0xFFFCu) | wtag;
    unsigned p1 = (unsigned)__shfl_xor((int)own, 1, 64);
    unsigned v32 = (lr & 1) ? ((own << 16) | p1) : (own | (p1 << 16));
    unsigned o2 = (unsigned)__shfl_xor((int)v32, 2, 64);
    u64 v64 = (lr & 2) ? (((u64)v32 << 32) | (u64)o2) : (((u64)o2 << 32) | (u64)v32);
    if ((lr & 3) == q) w = v64;
  }
  return w;
}

// LDS input-weight slice: 96 rows (3 gates x 32 own cols) x 64 k8-units, XOR-swizzled.
__device__ inline f16x8 ldwI(const f16* base, int row, int u8) {
  return *(const f16x8*)(base + ((size_t)row * 64 + (size_t)(u8 ^ (row & 7))) * 8);
}

}  // namespace gru

// ---------------- prep kernels ----------------

__global__ void gru_k_pe(float* pe) {
  int idx = blockIdx.x * 256 + threadIdx.x;
  if (idx >= 1024 * 512) return;
  int t = idx >> 9, d = idx & 511;
  int jj = d >> 1;
  float freq = expf(-logf(10000.f) * (float)(2 * jj) * (1.f / 512.f));
  float ang = (float)t * freq;
  pe[idx] = (d & 1) ? cosf(ang) : sinf(ang);
}

__global__ void gru_k_x16(const float* __restrict__ x, const float* __restrict__ pe,
                          f16* __restrict__ x16) {
  int d = blockIdx.x * 256 + threadIdx.x;  // grid.x = 2
  int t = blockIdx.y, b = blockIdx.z;
  float v = x[((size_t)b * 1024 + t) * 512 + d] + pe[t * 512 + d];
  x16[((size_t)t * 64 + b) * 512 + d] = (f16)v;
}

__global__ void gru_k_f16(const float* __restrict__ src, f16* __restrict__ dst, int n) {
  int i = blockIdx.x * 256 + threadIdx.x;
  if (i < n) dst[i] = (f16)src[i];
}

// ---------------- main persistent kernel ----------------
// 4 groups x 16 batch rows. XCD = wg%8: g = xcd>>1, layer = xcd&1.
// 32 WGs per XCD; each owns 32 hidden cols (c0 = slot*32). Self-recurrence
// exchange is INTRA-XCD (plain store -> shared L2 -> sc0 read) with per-f16
// tags; canonical sc0sc1 ring guarantees correctness if locality fails.
// Weights: wih slice in LDS (96KB); whh K-quarter + wih1 K-half1 quarter in
// persistent VGPRs -> zero per-step weight traffic.
// h0->h1 handoff: relay WG per L1 XCD coh-reads OLD h0 (L0 leads 16+ steps,
// visibility complete) and republishes into its own L2 for the other 31 WGs.

__global__ __launch_bounds__(WGSZ, 1) void gru_main(gru::Args A) {
  using namespace gru;
  __shared__ SMem sm;
  const int wg = blockIdx.x, tid = threadIdx.x;
  const int xcd = wg & 7, slot = wg >> 3;
  const int g = xcd >> 1;
  const bool isL0 = (xcd & 1) == 0;
  const int c0 = slot * 32;
  const int wave = tid >> 6, lane = tid & 63;
  const int lr = lane & 15, lk8 = lane >> 4;
  const int lk = lk8 * 8, dr = lk8 * 4;
  const bool relay = (slot == 0);

  const size_t RS = (size_t)16 * 1024;  // ring-slot stride (f16)
  f16* hl0 = A.hl + ((size_t)(g * 2 + 0) * RL) * RS;
  f16* hl1 = A.hl + ((size_t)(g * 2 + 1) * RL) * RS;
  f16* hc0 = A.hc + ((size_t)(g * 2 + 0) * RC) * RS;
  f16* hc1 = A.hc + ((size_t)(g * 2 + 1) * RC) * RS;
  f16* hm0g = A.hm0 + ((size_t)g * RL) * RS;
  f16* hlS = isL0 ? hl0 : hl1;
  f16* hcS = isL0 ? hc0 : hc1;
  unsigned* prog = A.prog + (size_t)g * 1024;

  const f16* Wi = isL0 ? A.wih0 : A.wih1;
  const f16* Wh = isL0 ? A.whh0 : A.whh1;
  const int WKi = isL0 ? 512 : 1024;
  const float* bI = isL0 ? A.bih0 : A.bih1;
  const float* bH = isL0 ? A.bhh0 : A.bhh1;

  __threadfence();  // cross-replay cache hygiene (once)

  // LDS input-weight slice: 96 rows x 64 k8 (L0: full K=512; L1: K-half [0,512))
  for (int u = tid; u < 96 * 64; u += WGSZ) {
    int row = u >> 6, k8 = u & 63;
    int gate = row >> 5, cidx = row & 31;
    f16x8 v = *(const f16x8*)(Wi + (size_t)(gate * 1024 + c0 + cidx) * WKi + k8 * 8);
    *(f16x8*)(sm.wI + ((size_t)row * 64 + (size_t)(k8 ^ (row & 7))) * 8) = v;
  }
  for (int i = tid; i < 16 * 32; i += WGSZ) ((float*)sm.hm)[i] = 0.f;

  // Persistent registers: whh K-quarter (6 tiles x 8 ks); L1 also wih1
  // K-half1 quarter (6 x 4). Fully unrolled -> static indices (reg-resident).
  f16x8 rH[6][8];
  f16x8 rI[6][4];
  {
    const int kqh = wave * 256;
#pragma unroll
    for (int idx = 0; idx < 6; ++idx) {
      const int gt = idx >> 1, T = idx & 1;
      const f16* wp = Wh + (size_t)(gt * 1024 + c0 + T * 16 + lr) * 1024 + kqh + lk;
#pragma unroll
      for (int ks = 0; ks < 8; ++ks) rH[idx][ks] = *(const f16x8*)(wp + ks * 32);
      if (!isL0) {
        const f16* wq = Wi + (size_t)(gt * 1024 + c0 + T * 16 + lr) * 1024 + 512 + wave * 128 + lk;
#pragma unroll
        for (int ks = 0; ks < 4; ++ks) rI[idx][ks] = *(const f16x8*)(wq + ks * 32);
      } else {
#pragma unroll
        for (int ks = 0; ks < 4; ++ks) rI[idx][ks] = 0;
      }
    }
  }

  // biases for own 32 cols (2 tiles x r/z/n)
  float bIr[2], bHr[2], bIz[2], bHz[2], bIn[2], bHn[2];
#pragma unroll
  for (int T = 0; T < 2; ++T) {
    int gc = c0 + T * 16 + lr;
    bIr[T] = bI[gc];        bHr[T] = bH[gc];
    bIz[T] = bI[1024 + gc]; bHz[T] = bH[1024 + gc];
    bIn[T] = bI[2048 + gc]; bHn[T] = bH[2048 + gc];
  }
  __syncthreads();

  for (int t = 0; t < 1024; ++t) {
    // L0 lead guard vs canonical ring (RC=32): every 8 steps, cap lead ~23. Capped spin.
    if (isL0 && ((t & 7) == 0) && t >= 24 && wave == 0) {
      const int need = t - 16;
      for (int it = 0; it < BAIL; ++it) {
        unsigned v = (lane < 32) ? aldu(prog + lane * 32) : 0xffffffffu;
        if (__all((int)v >= need)) break;
        __builtin_amdgcn_s_sleep(8);
      }
    }

    f32x4 acc4[4];  // r(T0,T1), z(T0,T1)
    f32x4 aI[2], aH[2];
#pragma unroll
    for (int i = 0; i < 4; ++i) acc4[i] = (f32x4){0, 0, 0, 0};
    aI[0] = aI[1] = aH[0] = aH[1] = (f32x4){0, 0, 0, 0};

    // ================= input part =================
    if (isL0) {
      const f16* xp = A.x16 + ((size_t)t * 64 + g * 16 + lr) * 512 + wave * 128 + lk;
      f16x8 af[4];
#pragma unroll
      for (int ks = 0; ks < 4; ++ks) af[ks] = *(const f16x8*)(xp + ks * 32);
#pragma unroll
      for (int idx = 0; idx < 6; ++idx) {
        const int gt = idx >> 1, T = idx & 1;
        const int row = gt * 32 + T * 16 + lr;
#pragma unroll
        for (int ks = 0; ks < 4; ++ks) {
          f16x8 b = ldwI(sm.wI, row, wave * 16 + ks * 4 + lk8);
          if (gt < 2) acc4[gt * 2 + T] = mf(af[ks], b, acc4[gt * 2 + T]);
          else aI[T] = mf(af[ks], b, aI[T]);
        }
      }
    } else {
      // h0(t): relay publishes to the XCD-local mirror; others read locally.
      const unsigned ep = 0x10001u * tag_of(t);
      const size_t ro_lo = (size_t)lr * 1024 + wave * 128 + lk;
      const size_t ro_hi = ro_lo + 512;
      const size_t cts = ((size_t)(t & (RC - 1))) * RS;
      const size_t mts = ((size_t)(t & (RL - 1))) * RS;
      frag4 iaL, iaH;
      if (relay) {
        iaL = ld4_val(hc0 + cts + ro_lo, ep);
        iaH = ld4_val(hc0 + cts + ro_hi, ep);
        f16* mp = hm0g + mts;
#pragma unroll
        for (int ks = 0; ks < 4; ++ks) {
          *(f16x8*)(mp + ro_lo + ks * 32) = iaL.v[ks];   // plain -> own L2
          *(f16x8*)(mp + ro_hi + ks * 32) = iaH.v[ks];
        }
      } else {
        iaL = ld4_fast(hm0g + mts + ro_lo, hc0 + cts + ro_lo, ep);
        iaH = ld4_fast(hm0g + mts + ro_hi, hc0 + cts + ro_hi, ep);
      }
#pragma unroll
      for (int idx = 0; idx < 6; ++idx) {
        const int gt = idx >> 1, T = idx & 1;
        const int row = gt * 32 + T * 16 + lr;
#pragma unroll
        for (int ks = 0; ks < 4; ++ks) {  // K-half0 from LDS
          f16x8 b = ldwI(sm.wI, row, wave * 16 + ks * 4 + lk8);
          if (gt < 2) acc4[gt * 2 + T] = mf(iaL.v[ks], b, acc4[gt * 2 + T]);
          else aI[T] = mf(iaL.v[ks], b, aI[T]);
        }
#pragma unroll
        for (int ks = 0; ks < 4; ++ks) {  // K-half1 from persistent regs
          if (gt < 2) acc4[gt * 2 + T] = mf(iaH.v[ks], rI[idx][ks], acc4[gt * 2 + T]);
          else aI[T] = mf(iaH.v[ks], rI[idx][ks], aI[T]);
        }
      }
    }

    // ================= self part: h_self(t-1), intra-XCD =================
    if (t > 0) {
      const unsigned ep = 0x10001u * tag_of(t - 1);
      const size_t ro = (size_t)lr * 1024 + wave * 256 + lk;
      const size_t lts = ((size_t)((t - 1) & (RL - 1))) * RS;
      const size_t cts = ((size_t)((t - 1) & (RC - 1))) * RS;
      frag4 s0 = ld4_fast(hlS + lts + ro, hcS + cts + ro, ep);
      frag4 s1 = ld4_fast(hlS + lts + ro + 128, hcS + cts + ro + 128, ep);
#pragma unroll
      for (int idx = 0; idx < 6; ++idx) {
        const int gt = idx >> 1, T = idx & 1;
#pragma unroll
        for (int ks = 0; ks < 8; ++ks) {
          f16x8 a = (ks < 4) ? s0.v[ks] : s1.v[ks - 4];
          if (gt < 2) acc4[gt * 2 + T] = mf(a, rH[idx][ks], acc4[gt * 2 + T]);
          else aH[T] = mf(a, rH[idx][ks], aH[T]);
        }
      }
    }

    // ================= reduce waves 1..3 -> 0, gates, store =================
    if (wave) {
      float* s = &sm.sc[wave - 1][0][0][lane];
#pragma unroll
      for (int q = 0; q < 4; ++q) {
        s[(0 * 4 + q) * 64] = acc4[0][q]; s[(1 * 4 + q) * 64] = acc4[1][q];
        s[(2 * 4 + q) * 64] = acc4[2][q]; s[(3 * 4 + q) * 64] = acc4[3][q];
        s[(4 * 4 + q) * 64] = aI[0][q];   s[(5 * 4 + q) * 64] = aI[1][q];
        s[(6 * 4 + q) * 64] = aH[0][q];   s[(7 * 4 + q) * 64] = aH[1][q];
      }
    }
    __syncthreads();
    if (wave == 0) {
#pragma unroll
      for (int wv = 0; wv < 3; ++wv) {
        const float* s = &sm.sc[wv][0][0][lane];
#pragma unroll
        for (int q = 0; q < 4; ++q) {
          acc4[0][q] += s[(0 * 4 + q) * 64]; acc4[1][q] += s[(1 * 4 + q) * 64];
          acc4[2][q] += s[(2 * 4 + q) * 64]; acc4[3][q] += s[(3 * 4 + q) * 64];
          aI[0][q] += s[(4 * 4 + q) * 64];   aI[1][q] += s[(5 * 4 + q) * 64];
          aH[0][q] += s[(6 * 4 + q) * 64];   aH[1][q] += s[(7 * 4 + q) * 64];
        }
      }
      const unsigned wt = tag_of(t);
      const size_t lts = ((size_t)(t & (RL - 1))) * RS;
      const size_t cts = ((size_t)(t & (RC - 1))) * RS;
#pragma unroll
      for (int T = 0; T < 2; ++T) {
        float hn4[4];
#pragma unroll
        for (int q = 0; q < 4; ++q) {
          float r = sigf(acc4[0 + T][q] + bIr[T] + bHr[T]);
          float z = sigf(acc4[2 + T][q] + bIz[T] + bHz[T]);
          float n = tanh_fast(aI[T][q] + bIn[T] + r * (aH[T][q] + bHn[T]));
          float hp = sm.hm[dr + q][T * 16 + lr];
          float hn = n + z * (hp - n);
          sm.hm[dr + q][T * 16 + lr] = hn;
          hn4[q] = hn;
        }
        u64 w = pack4(hn4, lr, wt);
        const int srow = dr + (lr & 3);
        const size_t off = (size_t)srow * 1024 + c0 + T * 16 + (lr & ~3);
        *(u64*)(hlS + lts + off) = w;   // local: own-XCD L2 fast path
        st8_sys(hcS + cts + off, w);    // canonical: always correct
      }
    }
    __syncthreads();
    if (!isL0 && tid == 0) astu(prog + slot * 32, (unsigned)(t + 1));
  }

  // ---- output projection (L1 XCDs): rows g*16..+15, cols slot*16..+15 ----
  if (!isL0) {
    const int oc0 = slot * 16;
    const unsigned ep = 0x10001u * gru::tag_of(1023);
    const size_t cts = ((size_t)(1023 & (RC - 1))) * RS;
    const size_t ro = (size_t)lr * 1024 + wave * 256 + lk;
    gru::frag4 f0 = gru::ld4_val(hc1 + cts + ro, ep);
    gru::frag4 f1 = gru::ld4_val(hc1 + cts + ro + 128, ep);
    f32x4 pacc = {0.f, 0.f, 0.f, 0.f};
    const f16* wb = A.wout + (size_t)(oc0 + lr) * 1024 + wave * 256 + lk;
#pragma unroll
    for (int ks = 0; ks < 8; ++ks) {
      f16x8 a = (ks < 4) ? f0.v[ks] : f1.v[ks - 4];
      pacc = gru::mf(a, *(const f16x8*)(wb + ks * 32), pacc);
    }
    if (wave) {
#pragma unroll
      for (int q = 0; q < 4; ++q) sm.sc[wave - 1][0][q][lane] = pacc[q];
    }
    __syncthreads();
    if (wave == 0) {
#pragma unroll
      for (int q = 0; q < 4; ++q) {
        float v = pacc[q] + sm.sc[0][0][q][lane] + sm.sc[1][0][q][lane] + sm.sc[2][0][q][lane];
        A.out[((size_t)(g * 16 + dr + q)) * 512 + oc0 + lr] = v + A.bout[oc0 + lr];
      }
    }
  }
}

// ---------------- host ----------------

extern "C" void kernel_launch(void* const* d_in, const int* in_sizes, int n_in,
                              void* d_out, int out_size, void* d_ws, size_t ws_size,
                              hipStream_t stream) {
  (void)in_sizes; (void)n_in; (void)out_size; (void)ws_size;
  const float* x = (const float*)d_in[0];
  const float* w_ih0 = (const float*)d_in[1];
  const float* w_hh0 = (const float*)d_in[2];
  const float* b_ih0 = (const float*)d_in[3];
  const float* b_hh0 = (const float*)d_in[4];
  const float* w_ih1 = (const float*)d_in[5];
  const float* w_hh1 = (const float*)d_in[6];
  const float* b_ih1 = (const float*)d_in[7];
  const float* b_hh1 = (const float*)d_in[8];
  const float* w_out = (const float*)d_in[9];
  const float* b_out = (const float*)d_in[10];

  char* ws = (char*)d_ws;
  size_t off = 0;
  auto alloc = [&](size_t b) {
    off = (off + 255) & ~(size_t)255;
    char* p = ws + off;
    off += b;
    return p;
  };

  float* pe = (float*)alloc((size_t)1024 * 512 * 4);
  f16* x16 = (f16*)alloc((size_t)1024 * 64 * 512 * 2);
  f16* wih0 = (f16*)alloc((size_t)3072 * 512 * 2);
  f16* whh0 = (f16*)alloc((size_t)3072 * 1024 * 2);
  f16* wih1 = (f16*)alloc((size_t)3072 * 1024 * 2);
  f16* whh1 = (f16*)alloc((size_t)3072 * 1024 * 2);
  f16* wout = (f16*)alloc((size_t)512 * 1024 * 2);
  f16* hl = (f16*)alloc((size_t)8 * RL * 16 * 1024 * 2);   // 4 MB
  f16* hc = (f16*)alloc((size_t)8 * RC * 16 * 1024 * 2);   // 8 MB
  f16* hm0 = (f16*)alloc((size_t)4 * RL * 16 * 1024 * 2);  // 2 MB
  unsigned* prog = (unsigned*)alloc((size_t)4 * 1024 * 4);
  // total ~102 MB (<= R13's proven footprint)

  (void)hipMemsetAsync(hl, 0, (size_t)8 * RL * 16 * 1024 * 2, stream);
  (void)hipMemsetAsync(hc, 0, (size_t)8 * RC * 16 * 1024 * 2, stream);
  (void)hipMemsetAsync(hm0, 0, (size_t)4 * RL * 16 * 1024 * 2, stream);
  (void)hipMemsetAsync(prog, 0, (size_t)4 * 1024 * 4, stream);

  gru_k_pe<<<(1024 * 512 + 255) / 256, 256, 0, stream>>>(pe);
  gru_k_x16<<<dim3(2, 1024, 64), 256, 0, stream>>>(x, pe, x16);
  gru_k_f16<<<(3072 * 512 + 255) / 256, 256, 0, stream>>>(w_ih0, wih0, 3072 * 512);
  gru_k_f16<<<(3072 * 1024 + 255) / 256, 256, 0, stream>>>(w_hh0, whh0, 3072 * 1024);
  gru_k_f16<<<(3072 * 1024 + 255) / 256, 256, 0, stream>>>(w_ih1, wih1, 3072 * 1024);
  gru_k_f16<<<(3072 * 1024 + 255) / 256, 256, 0, stream>>>(w_hh1, whh1, 3072 * 1024);
  gru_k_f16<<<(512 * 1024 + 255) / 256, 256, 0, stream>>>(w_out, wout, 512 * 1024);

  gru::Args A;
  A.x16 = x16;
  A.bih0 = b_ih0; A.bhh0 = b_hh0; A.bih1 = b_ih1; A.bhh1 = b_hh1; A.bout = b_out;
  A.wih0 = wih0; A.whh0 = whh0; A.wih1 = wih1; A.whh1 = whh1; A.wout = wout;
  A.hl = hl; A.hc = hc; A.hm0 = hm0;
  A.out = (float*)d_out;
  A.prog = prog;

  gru_main<<<dim3(NWG), dim3(WGSZ), 0, stream>>>(A);
}

// Round 16
// 11003.611 us; speedup vs baseline: 79.2293x; 79.2293x over previous
//
#include <hip/hip_runtime.h>
#include <cstdint>
#include <cstddef>

typedef _Float16 f16;
typedef _Float16 f16x8 __attribute__((ext_vector_type(8)));
typedef float f32x4 __attribute__((ext_vector_type(4)));
typedef unsigned u32x4 __attribute__((ext_vector_type(4)));
typedef unsigned long long u64;

#define NWG 256
#define WGSZ 256
#define RING 64   // canonical ring; 64 % 3 == 1 -> stale tag always differs
#define SRING 4   // staging ring (local-L2 fast path); 4 % 3 == 1

namespace gru {

__device__ inline f32x4 mf(f16x8 a, f16x8 b, f32x4 c) {
  return __builtin_amdgcn_mfma_f32_16x16x32_f16(a, b, c, 0, 0, 0);
}
__device__ inline float sigf(float x) { return 1.f / (1.f + __expf(-x)); }
__device__ inline float tanh_fast(float x) {
  float xx = fminf(fmaxf(x, -15.f), 15.f);
  float e = __expf(-2.f * xx);
  return (1.f - e) / (1.f + e);
}
__device__ inline unsigned tag_of(int t) { return 1u + (unsigned)(t % 3); }  // 1..3, never 0

struct SMem {
  f16 wA[48 * 1024];      // 96 KB: whh0 (L0) or whh1 (L1), swizzled
  f16 wB[48 * 512];       // 48 KB: wih0 (L0) or wih1 K-half 0 (L1), swizzled
  float sc[2][4][4][64];  // 8 KB pairwise-reduce scratch
  float hm[32][16];       // fp32 master h tile
  float bI[48], bH[48];
};

struct Args {
  const f16* x16;
  const float* bih0; const float* bhh0; const float* bih1; const float* bhh1; const float* bout;
  const f16* wih0; const f16* whh0; const f16* wih1; const f16* whh1; const f16* wout;
  f16* h0;   // canonical rings [2][RING][32][1024], tagged f16
  f16* h1;
  f16* h0s;  // staging rings [2][SRING][32][1024], tagged, local-L2 fast path
  f16* h1s;
  float* out;
  unsigned* flg;  // per group: [2048 unused][prod1: 64 x 128B-strided words]
};

__device__ inline unsigned aldu(const unsigned* p) {
  return __hip_atomic_load(p, __ATOMIC_RELAXED, __HIP_MEMORY_SCOPE_AGENT);
}
__device__ inline void astu(unsigned* p, unsigned v) {
  __hip_atomic_store(p, v, __ATOMIC_RELAXED, __HIP_MEMORY_SCOPE_AGENT);
}

struct frag16 { f16x8 v[16]; };

// Fully-coherent batched load: sc0 sc1 bypasses L1+L2, reads the IF/coherent
// point. Proven correct (R12). Early-clobber: outputs must not alias addr.
__device__ inline frag16 ld16_coh(const f16* p) {
  frag16 f;
  asm volatile(
      "global_load_dwordx4 %0, %16, off sc0 sc1\n\t"
      "global_load_dwordx4 %1, %16, off offset:64 sc0 sc1\n\t"
      "global_load_dwordx4 %2, %16, off offset:128 sc0 sc1\n\t"
      "global_load_dwordx4 %3, %16, off offset:192 sc0 sc1\n\t"
      "global_load_dwordx4 %4, %16, off offset:256 sc0 sc1\n\t"
      "global_load_dwordx4 %5, %16, off offset:320 sc0 sc1\n\t"
      "global_load_dwordx4 %6, %16, off offset:384 sc0 sc1\n\t"
      "global_load_dwordx4 %7, %16, off offset:448 sc0 sc1\n\t"
      "global_load_dwordx4 %8, %16, off offset:512 sc0 sc1\n\t"
      "global_load_dwordx4 %9, %16, off offset:576 sc0 sc1\n\t"
      "global_load_dwordx4 %10, %16, off offset:640 sc0 sc1\n\t"
      "global_load_dwordx4 %11, %16, off offset:704 sc0 sc1\n\t"
      "global_load_dwordx4 %12, %16, off offset:768 sc0 sc1\n\t"
      "global_load_dwordx4 %13, %16, off offset:832 sc0 sc1\n\t"
      "global_load_dwordx4 %14, %16, off offset:896 sc0 sc1\n\t"
      "global_load_dwordx4 %15, %16, off offset:960 sc0 sc1\n\t"
      "s_waitcnt vmcnt(0)"
      : "=&v"(f.v[0]), "=&v"(f.v[1]), "=&v"(f.v[2]), "=&v"(f.v[3]),
        "=&v"(f.v[4]), "=&v"(f.v[5]), "=&v"(f.v[6]), "=&v"(f.v[7]),
        "=&v"(f.v[8]), "=&v"(f.v[9]), "=&v"(f.v[10]), "=&v"(f.v[11]),
        "=&v"(f.v[12]), "=&v"(f.v[13]), "=&v"(f.v[14]), "=&v"(f.v[15])
      : "v"(p)
      : "memory");
  return f;
}

// L2-path batched load: sc0 only (bypass L1, served by local XCD L2; misses
// fill from the coherent point). Tags decide whether the content is usable.
__device__ inline frag16 ld16_l2(const f16* p) {
  frag16 f;
  asm volatile(
      "global_load_dwordx4 %0, %16, off sc0\n\t"
      "global_load_dwordx4 %1, %16, off offset:64 sc0\n\t"
      "global_load_dwordx4 %2, %16, off offset:128 sc0\n\t"
      "global_load_dwordx4 %3, %16, off offset:192 sc0\n\t"
      "global_load_dwordx4 %4, %16, off offset:256 sc0\n\t"
      "global_load_dwordx4 %5, %16, off offset:320 sc0\n\t"
      "global_load_dwordx4 %6, %16, off offset:384 sc0\n\t"
      "global_load_dwordx4 %7, %16, off offset:448 sc0\n\t"
      "global_load_dwordx4 %8, %16, off offset:512 sc0\n\t"
      "global_load_dwordx4 %9, %16, off offset:576 sc0\n\t"
      "global_load_dwordx4 %10, %16, off offset:640 sc0\n\t"
      "global_load_dwordx4 %11, %16, off offset:704 sc0\n\t"
      "global_load_dwordx4 %12, %16, off offset:768 sc0\n\t"
      "global_load_dwordx4 %13, %16, off offset:832 sc0\n\t"
      "global_load_dwordx4 %14, %16, off offset:896 sc0\n\t"
      "global_load_dwordx4 %15, %16, off offset:960 sc0\n\t"
      "s_waitcnt vmcnt(0)"
      : "=&v"(f.v[0]), "=&v"(f.v[1]), "=&v"(f.v[2]), "=&v"(f.v[3]),
        "=&v"(f.v[4]), "=&v"(f.v[5]), "=&v"(f.v[6]), "=&v"(f.v[7]),
        "=&v"(f.v[8]), "=&v"(f.v[9]), "=&v"(f.v[10]), "=&v"(f.v[11]),
        "=&v"(f.v[12]), "=&v"(f.v[13]), "=&v"(f.v[14]), "=&v"(f.v[15])
      : "v"(p)
      : "memory");
  return f;
}

// tag-validate: low 2 bits of every f16 must equal the step tag.
__device__ inline int vfrag(const frag16& f, unsigned ep) {
  unsigned acc = 0;
#pragma unroll
  for (int r = 0; r < 16; ++r) {
    u32x4 w = __builtin_bit_cast(u32x4, f.v[r]);
    acc |= ((w[0] & 0x30003u) ^ ep) | ((w[1] & 0x30003u) ^ ep) |
           ((w[2] & 0x30003u) ^ ep) | ((w[3] & 0x30003u) ^ ep);
  }
  return acc == 0;
}

__device__ inline frag16 ld16_val(const f16* p, unsigned ep) {
  frag16 f = ld16_coh(p);
  while (!__all(vfrag(f, ep))) {
    __builtin_amdgcn_s_sleep(1);
    f = ld16_coh(p);
  }
  return f;
}

// Pack lane's 4 gate outputs into one u64 (4 adjacent cols of one row) via
// 2x shfl_xor; each f16's low 2 bits replaced by the step tag.
__device__ inline u64 pack4(const float* hn4, int lr, unsigned wtag) {
  u64 w = 0;
#pragma unroll
  for (int q = 0; q < 4; ++q) {
    f16 h = (f16)hn4[q];
    unsigned own = ((unsigned)__builtin_bit_cast(unsigned short, h) & 0xFFFCu) | wtag;
    unsigned p1 = (unsigned)__shfl_xor((int)own, 1, 64);
    unsigned v32 = (lr & 1) ? ((own << 16) | p1) : (own | (p1 << 16));
    unsigned o2 = (unsigned)__shfl_xor((int)v32, 2, 64);
    u64 v64 = (lr & 2) ? (((u64)v32 << 32) | (u64)o2) : (((u64)o2 << 32) | (u64)v32);
    if ((lr & 3) == q) w = v64;
  }
  return w;
}

// 16B coherent write-through store (canonical copy).
__device__ inline void st16_coh(f16* p, u32x4 v) {
  asm volatile("global_store_dwordx4 %0, %1, off sc0 sc1" :: "v"(p), "v"(v) : "memory");
}

template <int K8, int SK8>
__device__ void load_w(f16* dst, const f16* W, int j) {
  for (int u = threadIdx.x; u < 48 * K8; u += WGSZ) {
    int row = u / K8, k8 = u - row * K8;
    int gcol = (row >> 4) * 1024 + j * 16 + (row & 15);
    f16x8 v = *(const f16x8*)(W + (size_t)gcol * (size_t)(SK8 * 8) + (size_t)k8 * 8);
    *(f16x8*)(dst + ((size_t)row * K8 + (size_t)(k8 ^ (row & 7))) * 8) = v;
  }
}

template <int K8>
__device__ inline f16x8 ldb(const f16* base, int row, int u8) {
  return *(const f16x8*)(base + ((size_t)row * K8 + (size_t)(u8 ^ (row & 7))) * 8);
}

}  // namespace gru

// ---------------- prep kernels ----------------

__global__ void gru_k_pe(float* pe) {
  int idx = blockIdx.x * 256 + threadIdx.x;
  if (idx >= 1024 * 512) return;
  int t = idx >> 9, d = idx & 511;
  int jj = d >> 1;
  float freq = expf(-logf(10000.f) * (float)(2 * jj) * (1.f / 512.f));
  float ang = (float)t * freq;
  pe[idx] = (d & 1) ? cosf(ang) : sinf(ang);
}

__global__ void gru_k_x16(const float* __restrict__ x, const float* __restrict__ pe,
                          f16* __restrict__ x16) {
  int d = blockIdx.x * 256 + threadIdx.x;  // grid.x = 2
  int t = blockIdx.y, b = blockIdx.z;
  float v = x[((size_t)b * 1024 + t) * 512 + d] + pe[t * 512 + d];
  x16[((size_t)t * 64 + b) * 512 + d] = (f16)v;
}

__global__ void gru_k_f16(const float* __restrict__ src, f16* __restrict__ dst, int n) {
  int i = blockIdx.x * 256 + threadIdx.x;
  if (i < n) dst[i] = (f16)src[i];
}

// ---------------- main persistent pipelined kernel ----------------
// 2 groups x 32 rows; xcd = wg%8: grp = xcd>>2, role = (xcd>>1)&1,
// wgid = ((xcd&1)<<5)|(wg>>3).
// R13 (best known): tag-routed cache paths to cut coherent-point bytes:
//  - producers dual-write: canonical (sc0 sc1) + staging ring (normal cached
//    store); consumers try staging (sc0, cap 2, sticky-disable after 6
//    consecutive fails) -> fallback canonical spin.
//  - gf (h0(t), written ~40 steps early by the free-running L0): sc0-cached
//    read of the canonical address -> one IF fill per XCD, 32x dedup.
// Tags (R12) make every fast path safe: stale reads self-detect and fall
// back to the proven sc0sc1 coherent path.

__global__ __launch_bounds__(WGSZ, 1) void gru_main(gru::Args A) {
  using namespace gru;
  __shared__ SMem sm;
  const int wg = blockIdx.x, tid = threadIdx.x;
  const int xcd = wg & 7, slot = wg >> 3;
  const int grp = xcd >> 2;
  const bool isL0 = ((xcd >> 1) & 1) == 0;
  const int wgid = ((xcd & 1) << 5) | slot;
  const int j = wgid;
  const int wave = tid >> 6, lane = tid & 63;
  const int lr = lane & 15, lk8 = lane >> 4;
  const int lk = lk8 * 8, dr = lk8 * 4;
  const int rt = wave >> 1, kh = wave & 1;
  const int rowbase = rt * 16;
  const int gb = grp * 32;

  f16* h0g = A.h0 + (size_t)grp * RING * 32 * 1024;
  f16* h1g = A.h1 + (size_t)grp * RING * 32 * 1024;
  f16* h0sg = A.h0s + (size_t)grp * SRING * 32 * 1024;
  f16* h1sg = A.h1s + (size_t)grp * SRING * 32 * 1024;
  unsigned* prod1 = A.flg + (size_t)grp * 2 * 2048 + 2048;

  __threadfence();  // once: cross-replay hygiene (wb+inv all cache levels)

  ((float*)sm.hm)[tid] = 0.f;
  ((float*)sm.hm)[tid + 256] = 0.f;

  if (isL0) {
    load_w<128, 128>(sm.wA, A.whh0, j);
    load_w<64, 64>(sm.wB, A.wih0, j);
    if (tid < 48) {
      int gcol = (tid >> 4) * 1024 + j * 16 + (tid & 15);
      sm.bI[tid] = A.bih0[gcol];
      sm.bH[tid] = A.bhh0[gcol];
    }
  } else {
    load_w<128, 128>(sm.wA, A.whh1, j);
    load_w<64, 128>(sm.wB, A.wih1, j);  // wih1 K-half 0 in LDS
    if (tid < 48) {
      int gcol = (tid >> 4) * 1024 + j * 16 + (tid & 15);
      sm.bI[tid] = A.bih1[gcol];
      sm.bH[tid] = A.bhh1[gcol];
    }
  }
  __syncthreads();

  int consec = 0;      // consecutive staging failures (wave-uniform)
  bool fastok = true;  // sticky staging enable

  if (isL0) {
    // =============== layer-0 ===============
    f16x8 xf[2][8];
    {
      const f16* xp = A.x16 + ((size_t)0 * 64 + gb + rowbase + lr) * 512 + kh * 256 + lk;
#pragma unroll
      for (int q2 = 0; q2 < 8; ++q2) xf[0][q2] = *(const f16x8*)(xp + q2 * 32);
    }
    for (int t = 0; t < 1024; ++t) {
      const int cur = t & 1;
      if (((t & 15) == 0) && t >= 48 && wave == 0) {  // amortized ring guard
        const int need = t - 40;
        const unsigned* p1 = prod1 + lane * 32;
        while (!__all((int)aldu(p1) >= need)) __builtin_amdgcn_s_sleep(8);
      }
      f32x4 a0 = {0.f, 0.f, 0.f, 0.f}, a1 = a0, a2 = a0, a3 = a0;
#pragma unroll
      for (int q2 = 0; q2 < 8; ++q2) {
        const int u8 = (kh * 8 + q2) * 4 + lk8;
        a0 = mf(xf[cur][q2], ldb<64>(sm.wB, lr, u8), a0);
        a1 = mf(xf[cur][q2], ldb<64>(sm.wB, 16 + lr, u8), a1);
        a2 = mf(xf[cur][q2], ldb<64>(sm.wB, 32 + lr, u8), a2);  // i_n
      }
      if (t + 1 < 1024) {
        const f16* xp = A.x16 + ((size_t)(t + 1) * 64 + gb + rowbase + lr) * 512 + kh * 256 + lk;
#pragma unroll
        for (int q2 = 0; q2 < 8; ++q2) xf[cur ^ 1][q2] = *(const f16x8*)(xp + q2 * 32);
      }
      // ---- hf = h0(t-1): staging fast path -> canonical fallback ----
      frag16 hf;
      if (t == 0) {
#pragma unroll
        for (int q2 = 0; q2 < 16; ++q2) hf.v[q2] = 0;
      } else {
        const unsigned ep = 0x10001u * tag_of(t - 1);
        bool got = false;
        if (fastok) {
          const f16* sp = h0sg + (((size_t)((t - 1) & (SRING - 1))) * 32 + rowbase + lr) * 1024 + kh * 512 + lk;
          frag16 f = ld16_l2(sp);
          int tries = 0;
          for (;;) {
            if (__all(vfrag(f, ep))) { hf = f; got = true; break; }
            if (++tries > 2) break;
            __builtin_amdgcn_s_sleep(1);
            f = ld16_l2(sp);
          }
          if (got) consec = 0;
          else if (++consec >= 6) fastok = false;
        }
        if (!got) {
          const f16* hp = h0g + ((size_t)((t + RING - 1) & (RING - 1)) * 32 + rowbase + lr) * 1024 + kh * 512 + lk;
          hf = ld16_val(hp, ep);
        }
      }
#pragma unroll
      for (int q2 = 0; q2 < 16; ++q2) {
        const int u8 = (kh * 16 + q2) * 4 + lk8;
        a0 = mf(hf.v[q2], ldb<128>(sm.wA, lr, u8), a0);
        a1 = mf(hf.v[q2], ldb<128>(sm.wA, 16 + lr, u8), a1);
        a3 = mf(hf.v[q2], ldb<128>(sm.wA, 32 + lr, u8), a3);  // h_n
      }
      if (kh) {
#pragma unroll
        for (int q = 0; q < 4; ++q) {
          sm.sc[rt][0][q][lane] = a0[q]; sm.sc[rt][1][q][lane] = a1[q];
          sm.sc[rt][2][q][lane] = a2[q]; sm.sc[rt][3][q][lane] = a3[q];
        }
      }
      __syncthreads();
      if (!kh) {
        float hn4[4];
#pragma unroll
        for (int q = 0; q < 4; ++q) {
          a0[q] += sm.sc[rt][0][q][lane]; a1[q] += sm.sc[rt][1][q][lane];
          a2[q] += sm.sc[rt][2][q][lane]; a3[q] += sm.sc[rt][3][q][lane];
        }
#pragma unroll
        for (int q = 0; q < 4; ++q) {
          const int row = rt * 16 + dr + q;
          float r = sigf(a0[q] + sm.bI[lr] + sm.bH[lr]);
          float z = sigf(a1[q] + sm.bI[16 + lr] + sm.bH[16 + lr]);
          float n = tanh_fast(a2[q] + sm.bI[32 + lr] + r * (a3[q] + sm.bH[32 + lr]));
          float hn = n + z * (sm.hm[row][lr] - n);
          sm.hm[row][lr] = hn;
          hn4[q] = hn;
        }
        u64 w = pack4(hn4, lr, tag_of(t));
        unsigned wlo = (unsigned)w, whi = (unsigned)(w >> 32);
        unsigned plo = (unsigned)__shfl_xor((int)wlo, 4, 64);
        unsigned phi = (unsigned)__shfl_xor((int)whi, 4, 64);
        if ((lr & 4) == 0) {
          const int srow = rt * 16 + dr + (lr & 3);
          u32x4 v4 = {wlo, whi, plo, phi};
          const size_t co = (size_t)srow * 1024 + j * 16 + (lr & ~7);
          st16_coh(h0g + ((size_t)(t & (RING - 1)) * 32) * 1024 + co, v4);      // canonical
          *(u32x4*)(h0sg + ((size_t)(t & (SRING - 1)) * 32) * 1024 + co) = v4;  // staging (local L2)
        }
      }
      __syncthreads();
    }
  } else {
    // =============== layer-1 ===============
    for (int t = 0; t < 1024; ++t) {
      // ---- gf = h0(t): sc0-cached (L0 far ahead; one IF fill per XCD) ----
      const f16* gp = h0g + ((size_t)(t & (RING - 1)) * 32 + rowbase + lr) * 1024 + kh * 512 + lk;
      const unsigned epg = 0x10001u * tag_of(t);
      frag16 gf;
      {
        frag16 f = ld16_l2(gp);
        int tries = 0; bool ok = false;
        for (;;) {
          if (__all(vfrag(f, epg))) { gf = f; ok = true; break; }
          if (++tries > 2) break;
          __builtin_amdgcn_s_sleep(1);
          f = ld16_l2(gp);
        }
        if (!ok) gf = ld16_val(gp, epg);
      }
      // ---- hf = h1(t-1): staging fast path -> canonical fallback ----
      frag16 hf;
      if (t == 0) {
#pragma unroll
        for (int q2 = 0; q2 < 16; ++q2) hf.v[q2] = 0;
      } else {
        const unsigned ep = 0x10001u * tag_of(t - 1);
        bool got = false;
        if (fastok) {
          const f16* sp = h1sg + (((size_t)((t - 1) & (SRING - 1))) * 32 + rowbase + lr) * 1024 + kh * 512 + lk;
          frag16 f = ld16_l2(sp);
          int tries = 0;
          for (;;) {
            if (__all(vfrag(f, ep))) { hf = f; got = true; break; }
            if (++tries > 2) break;
            __builtin_amdgcn_s_sleep(1);
            f = ld16_l2(sp);
          }
          if (got) consec = 0;
          else if (++consec >= 6) fastok = false;
        }
        if (!got) {
          const f16* hp = h1g + ((size_t)((t + RING - 1) & (RING - 1)) * 32 + rowbase + lr) * 1024 + kh * 512 + lk;
          hf = ld16_val(hp, ep);
        }
      }
      f32x4 a0 = {0.f, 0.f, 0.f, 0.f}, a1 = a0, a2 = a0, a3 = a0;
      if (kh == 0) {
#pragma unroll
        for (int q2 = 0; q2 < 16; ++q2) {
          const int u8 = q2 * 4 + lk8;
          a0 = mf(gf.v[q2], ldb<64>(sm.wB, lr, u8), a0);
          a1 = mf(gf.v[q2], ldb<64>(sm.wB, 16 + lr, u8), a1);
          a2 = mf(gf.v[q2], ldb<64>(sm.wB, 32 + lr, u8), a2);  // i_n
        }
      } else {
        const f16* wb = A.wih1 + ((size_t)(j * 16 + lr)) * 1024 + 512 + lk;
#pragma unroll
        for (int q2 = 0; q2 < 16; ++q2) {
          const size_t o = (size_t)q2 * 32;
          a0 = mf(gf.v[q2], *(const f16x8*)(wb + o), a0);
          a1 = mf(gf.v[q2], *(const f16x8*)(wb + (size_t)1024 * 1024 + o), a1);
          a2 = mf(gf.v[q2], *(const f16x8*)(wb + (size_t)2048 * 1024 + o), a2);  // i_n
        }
      }
#pragma unroll
      for (int q2 = 0; q2 < 16; ++q2) {
        const int u8 = (kh * 16 + q2) * 4 + lk8;
        a0 = mf(hf.v[q2], ldb<128>(sm.wA, lr, u8), a0);
        a1 = mf(hf.v[q2], ldb<128>(sm.wA, 16 + lr, u8), a1);
        a3 = mf(hf.v[q2], ldb<128>(sm.wA, 32 + lr, u8), a3);  // h_n
      }
      if (kh) {
#pragma unroll
        for (int q = 0; q < 4; ++q) {
          sm.sc[rt][0][q][lane] = a0[q]; sm.sc[rt][1][q][lane] = a1[q];
          sm.sc[rt][2][q][lane] = a2[q]; sm.sc[rt][3][q][lane] = a3[q];
        }
      }
      __syncthreads();
      if (!kh) {
        float hn4[4];
#pragma unroll
        for (int q = 0; q < 4; ++q) {
          a0[q] += sm.sc[rt][0][q][lane]; a1[q] += sm.sc[rt][1][q][lane];
          a2[q] += sm.sc[rt][2][q][lane]; a3[q] += sm.sc[rt][3][q][lane];
        }
#pragma unroll
        for (int q = 0; q < 4; ++q) {
          const int row = rt * 16 + dr + q;
          float r = sigf(a0[q] + sm.bI[lr] + sm.bH[lr]);
          float z = sigf(a1[q] + sm.bI[16 + lr] + sm.bH[16 + lr]);
          float n = tanh_fast(a2[q] + sm.bI[32 + lr] + r * (a3[q] + sm.bH[32 + lr]));
          float hn = n + z * (sm.hm[row][lr] - n);
          sm.hm[row][lr] = hn;
          hn4[q] = hn;
        }
        u64 w = pack4(hn4, lr, tag_of(t));
        unsigned wlo = (unsigned)w, whi = (unsigned)(w >> 32);
        unsigned plo = (unsigned)__shfl_xor((int)wlo, 4, 64);
        unsigned phi = (unsigned)__shfl_xor((int)whi, 4, 64);
        if ((lr & 4) == 0) {
          const int srow = rt * 16 + dr + (lr & 3);
          u32x4 v4 = {wlo, whi, plo, phi};
          const size_t co = (size_t)srow * 1024 + j * 16 + (lr & ~7);
          st16_coh(h1g + ((size_t)(t & (RING - 1)) * 32) * 1024 + co, v4);      // canonical
          *(u32x4*)(h1sg + ((size_t)(t & (SRING - 1)) * 32) * 1024 + co) = v4;  // staging
        }
      }
      __syncthreads();
      if (tid == 0) astu(prod1 + wgid * 32, (unsigned)(t + 1));
    }

    // ---- output projection: out rows gb..gb+31 = h1(1023) @ w_out^T + b_out ----
    const int j2 = wgid & 31, rg2 = wgid >> 5;
    f32x4 acc = {0.f, 0.f, 0.f, 0.f};
    if (wave < 2) {
      const f16* Ah = h1g + ((size_t)(1023 & (RING - 1)) * 32 + rg2 * 16 + lr) * 1024 + wave * 512 + lk;
      const f16* Bp = A.wout + ((size_t)(j2 * 16 + lr)) * 1024 + wave * 512 + lk;
      frag16 hv = ld16_val(Ah, 0x10001u * gru::tag_of(1023));
#pragma unroll
      for (int q2 = 0; q2 < 16; ++q2)
        acc = mf(hv.v[q2], *(const f16x8*)(Bp + q2 * 32), acc);
    }
    if (wave == 1) {
#pragma unroll
      for (int q = 0; q < 4; ++q) sm.sc[0][0][q][lane] = acc[q];
    }
    __syncthreads();
    if (wave == 0) {
#pragma unroll
      for (int q = 0; q < 4; ++q) {
        float v = acc[q] + sm.sc[0][0][q][lane] + A.bout[j2 * 16 + lr];
        A.out[(gb + rg2 * 16 + dr + q) * 512 + j2 * 16 + lr] = v;
      }
    }
  }
}

// ---------------- host ----------------

extern "C" void kernel_launch(void* const* d_in, const int* in_sizes, int n_in,
                              void* d_out, int out_size, void* d_ws, size_t ws_size,
                              hipStream_t stream) {
  (void)in_sizes; (void)n_in; (void)out_size; (void)ws_size;
  const float* x = (const float*)d_in[0];
  const float* w_ih0 = (const float*)d_in[1];
  const float* w_hh0 = (const float*)d_in[2];
  const float* b_ih0 = (const float*)d_in[3];
  const float* b_hh0 = (const float*)d_in[4];
  const float* w_ih1 = (const float*)d_in[5];
  const float* w_hh1 = (const float*)d_in[6];
  const float* b_ih1 = (const float*)d_in[7];
  const float* b_hh1 = (const float*)d_in[8];
  const float* w_out = (const float*)d_in[9];
  const float* b_out = (const float*)d_in[10];

  char* ws = (char*)d_ws;
  size_t off = 0;
  auto alloc = [&](size_t b) {
    off = (off + 255) & ~(size_t)255;
    char* p = ws + off;
    off += b;
    return p;
  };

  float* pe = (float*)alloc((size_t)1024 * 512 * 4);
  f16* x16 = (f16*)alloc((size_t)1024 * 64 * 512 * 2);
  f16* wih0 = (f16*)alloc((size_t)3072 * 512 * 2);
  f16* whh0 = (f16*)alloc((size_t)3072 * 1024 * 2);
  f16* wih1 = (f16*)alloc((size_t)3072 * 1024 * 2);
  f16* whh1 = (f16*)alloc((size_t)3072 * 1024 * 2);
  f16* wout = (f16*)alloc((size_t)512 * 1024 * 2);
  f16* h0r = (f16*)alloc((size_t)2 * RING * 32 * 1024 * 2);
  f16* h1r = (f16*)alloc((size_t)2 * RING * 32 * 1024 * 2);
  f16* h0s = (f16*)alloc((size_t)2 * SRING * 32 * 1024 * 2);
  f16* h1s = (f16*)alloc((size_t)2 * SRING * 32 * 1024 * 2);
  unsigned* flg = (unsigned*)alloc((size_t)2 * 2 * 2048 * 4);

  // per-call init: rings + staging all tag-0 (invalid); counters zero.
  (void)hipMemsetAsync(h0r, 0, (size_t)2 * RING * 32 * 1024 * 2, stream);
  (void)hipMemsetAsync(h1r, 0, (size_t)2 * RING * 32 * 1024 * 2, stream);
  (void)hipMemsetAsync(h0s, 0, (size_t)2 * SRING * 32 * 1024 * 2, stream);
  (void)hipMemsetAsync(h1s, 0, (size_t)2 * SRING * 32 * 1024 * 2, stream);
  (void)hipMemsetAsync(flg, 0, (size_t)2 * 2 * 2048 * 4, stream);

  gru_k_pe<<<(1024 * 512 + 255) / 256, 256, 0, stream>>>(pe);
  gru_k_x16<<<dim3(2, 1024, 64), 256, 0, stream>>>(x, pe, x16);
  gru_k_f16<<<(3072 * 512 + 255) / 256, 256, 0, stream>>>(w_ih0, wih0, 3072 * 512);
  gru_k_f16<<<(3072 * 1024 + 255) / 256, 256, 0, stream>>>(w_hh0, whh0, 3072 * 1024);
  gru_k_f16<<<(3072 * 1024 + 255) / 256, 256, 0, stream>>>(w_ih1, wih1, 3072 * 1024);
  gru_k_f16<<<(3072 * 1024 + 255) / 256, 256, 0, stream>>>(w_hh1, whh1, 3072 * 1024);
  gru_k_f16<<<(512 * 1024 + 255) / 256, 256, 0, stream>>>(w_out, wout, 512 * 1024);

  gru::Args A;
  A.x16 = x16;
  A.bih0 = b_ih0; A.bhh0 = b_hh0; A.bih1 = b_ih1; A.bhh1 = b_hh1; A.bout = b_out;
  A.wih0 = wih0; A.whh0 = whh0; A.wih1 = wih1; A.whh1 = whh1; A.wout = wout;
  A.h0 = h0r; A.h1 = h1r;
  A.h0s = h0s; A.h1s = h1s;
  A.out = (float*)d_out;
  A.flg = flg;

  // Plain launch: 256 blocks x 1 block/CU (LDS-bound) on 256 CUs -> co-resident.
  gru_main<<<dim3(NWG), dim3(WGSZ), 0, stream>>>(A);
}